// Round 4
// baseline (668.574 us; speedup 1.0000x reference)
//
#include <hip/hip_runtime.h>
#include <math.h>

#define BB   2
#define SS   2048
#define HH   8
#define DD   64
#define HIDD 512
#define NT   (BB * SS)

// ---------------------------------------------------------------------------
// MFMA foundations (gfx950, v_mfma_f32_16x16x32_f16).
// Layout bundle (self-consistent with HW-verified D-mapping m89/m91):
//   A: lane l supplies A[m = l&15][k = (l>>4)*8 + i], i=0..7
//   B: lane l supplies B[k = (l>>4)*8 + i][n = l&15]
//   D: lane l holds   D[m = (l>>4)*4 + r][n = l&15], r=0..3
// f16x3 split: x = hi + lo (hi = f16(x), lo = f16(x-hi));
// A*B ~= Ahi*Bhi + Ahi*Blo + Alo*Bhi (dropped term ~2^-22 rel).
// ---------------------------------------------------------------------------
typedef _Float16 half8   __attribute__((ext_vector_type(8)));
typedef _Float16 half4_t __attribute__((ext_vector_type(4)));
typedef float    f32x4   __attribute__((ext_vector_type(4)));

__device__ __forceinline__ f32x4 mfma16(half8 a, half8 b, f32x4 c) {
    return __builtin_amdgcn_mfma_f32_16x16x32_f16(a, b, c, 0, 0, 0);
}

__device__ __forceinline__ void split_store(float4 v, _Float16* hp, _Float16* lp) {
    half4_t hv, lv;
    hv[0] = (_Float16)v.x; lv[0] = (_Float16)(v.x - (float)hv[0]);
    hv[1] = (_Float16)v.y; lv[1] = (_Float16)(v.y - (float)hv[1]);
    hv[2] = (_Float16)v.z; lv[2] = (_Float16)(v.z - (float)hv[2]);
    hv[3] = (_Float16)v.w; lv[3] = (_Float16)(v.w - (float)hv[3]);
    *(half4_t*)hp = hv;
    *(half4_t*)lp = lv;
}

// ---------------------------------------------------------------------------
// Projection GEMM: Y = X @ W^T + bias.  X [NT,HID], W [HID,HID] (W[o][k]).
// 64x64 tile, 256 thr = 4 waves (wave w -> rows 16w..16w+15, all 64 cols),
// BK=32 (one MFMA K per step), f16x3.
//   MODE 0: head-split write [B,H,S,D]
//   MODE 1: merged write     [B,S,HID]
//   MODE 2: transposed write [B,H,D,S]   (for V, so PV B-frags are contiguous)
// ---------------------------------------------------------------------------
#define PADK 40  // 32+8 halves: row stride 80B (16B-mult), spreads banks
template <int MODE>
__global__ __launch_bounds__(256) void proj_mfma(const float* __restrict__ X,
                                                 const float* __restrict__ W,
                                                 const float* __restrict__ bias,
                                                 float* __restrict__ Y) {
    alignas(16) __shared__ _Float16 Xh[64][PADK], Xl[64][PADK];
    alignas(16) __shared__ _Float16 Wh[64][PADK], Wl[64][PADK];

    const int tid = threadIdx.x;
    const int w  = tid >> 6;          // wave 0..3
    const int l  = tid & 63;
    const int lm = l & 15;            // A row / B col within 16
    const int lg = l >> 4;            // k-octet group
    const int row0 = blockIdx.x * 64;
    const int col0 = blockIdx.y * 64;

    f32x4 acc[4];
#pragma unroll
    for (int nt = 0; nt < 4; ++nt) acc[nt] = f32x4{0.f, 0.f, 0.f, 0.f};

    for (int kk = 0; kk < HIDD; kk += 32) {
        __syncthreads();
#pragma unroll
        for (int p = 0; p < 2; ++p) {
            const int idx = tid + p * 256;        // 0..511
            const int r = idx >> 3, c4 = idx & 7; // row, float4-col (of 8)
            float4 xv = *(const float4*)&X[(size_t)(row0 + r) * HIDD + kk + c4 * 4];
            split_store(xv, &Xh[r][c4 * 4], &Xl[r][c4 * 4]);
            float4 wv = *(const float4*)&W[(size_t)(col0 + r) * HIDD + kk + c4 * 4];
            split_store(wv, &Wh[r][c4 * 4], &Wl[r][c4 * 4]);
        }
        __syncthreads();

        half8 ah = *(const half8*)&Xh[w * 16 + lm][lg * 8];
        half8 al = *(const half8*)&Xl[w * 16 + lm][lg * 8];
#pragma unroll
        for (int nt = 0; nt < 4; ++nt) {
            half8 bh = *(const half8*)&Wh[nt * 16 + lm][lg * 8];
            half8 bl = *(const half8*)&Wl[nt * 16 + lm][lg * 8];
            acc[nt] = mfma16(ah, bh, acc[nt]);
            acc[nt] = mfma16(ah, bl, acc[nt]);
            acc[nt] = mfma16(al, bh, acc[nt]);
        }
    }

    if constexpr (MODE == 2) {
        __shared__ float Ts[64][65];  // stride 65: read pattern is 2-way (free)
        __syncthreads();
#pragma unroll
        for (int nt = 0; nt < 4; ++nt) {
            const float bv = bias[col0 + nt * 16 + lm];
#pragma unroll
            for (int r = 0; r < 4; ++r)
                Ts[w * 16 + lg * 4 + r][nt * 16 + lm] = acc[nt][r] + bv;
        }
        __syncthreads();
        // coalesced transposed store: Vt[b][h][d][s]
        const int c  = tid >> 2;            // local d
        const int sb = (tid & 3) * 16;      // local s base
        const int b  = row0 >> 11;
        const int h  = col0 >> 6;
        float* dst = Y + (((size_t)b * HH + h) * DD + c) * SS + (row0 & (SS - 1));
#pragma unroll
        for (int u = 0; u < 4; ++u) {
            const int s0 = sb + u * 4;
            float4 o = {Ts[s0][c], Ts[s0 + 1][c], Ts[s0 + 2][c], Ts[s0 + 3][c]};
            *(float4*)&dst[s0] = o;
        }
    } else {
#pragma unroll
        for (int nt = 0; nt < 4; ++nt) {
            const int ncol = col0 + nt * 16 + lm;
            const float bv = bias[ncol];
#pragma unroll
            for (int r = 0; r < 4; ++r) {
                const int mrow = row0 + w * 16 + lg * 4 + r;
                const float val = acc[nt][r] + bv;
                if (MODE == 0) {
                    const int b = mrow >> 11, s = mrow & (SS - 1);
                    const int h = ncol >> 6, d = ncol & 63;
                    Y[(((size_t)b * HH + h) * SS + s) * DD + d] = val;
                } else {
                    Y[(size_t)mrow * HIDD + ncol] = val;
                }
            }
        }
    }
}

// ---------------------------------------------------------------------------
// Scores: raw scaled+masked scores -> attn, online (m,l) -> ws.
// Block = (b,h) x 64 q-rows; wave w -> q rows 16w..16w+15; k-tiles of 64.
// QK^T via f16x3 MFMA (Q,K both row-major [pos][d] in LDS).
// ---------------------------------------------------------------------------
#define PADD 72  // 64+8 halves: row stride 144B (16B-mult)
__global__ __launch_bounds__(256) void scores_mfma(
    const float* __restrict__ qh, const float* __restrict__ kh,
    const int* __restrict__ mask, float* __restrict__ attn,
    float* __restrict__ mstat, float* __restrict__ lstat) {
    alignas(16) __shared__ _Float16 Qh[64][PADD], Ql[64][PADD];
    alignas(16) __shared__ _Float16 Kh[64][PADD], Kl[64][PADD];

    const int tid = threadIdx.x;
    const int w  = tid >> 6;
    const int l  = tid & 63;
    const int lm = l & 15;
    const int lg = l >> 4;
    const int bh = blockIdx.y;
    const int b  = bh >> 3;
    const int q0 = blockIdx.x * 64;

    {   // stage Q tile once: rows q, 64 d = 16 float4 per row
        const float* qsrc = qh + ((size_t)bh * SS + q0) * DD;
#pragma unroll
        for (int p = 0; p < 4; ++p) {
            const int idx = tid + p * 256;
            const int r = idx >> 4, c4 = idx & 15;
            float4 v = *(const float4*)&qsrc[(size_t)r * DD + c4 * 4];
            split_store(v, &Qh[r][c4 * 4], &Ql[r][c4 * 4]);
        }
    }

    float mreg[4], lsum[4];
#pragma unroll
    for (int r = 0; r < 4; ++r) { mreg[r] = -INFINITY; lsum[r] = 0.f; }

    for (int k0 = 0; k0 < SS; k0 += 64) {
        __syncthreads();
        {   // stage K tile
            const float* ksrc = kh + ((size_t)bh * SS + k0) * DD;
#pragma unroll
            for (int p = 0; p < 4; ++p) {
                const int idx = tid + p * 256;
                const int r = idx >> 4, c4 = idx & 15;
                float4 v = *(const float4*)&ksrc[(size_t)r * DD + c4 * 4];
                split_store(v, &Kh[r][c4 * 4], &Kl[r][c4 * 4]);
            }
        }
        __syncthreads();

        half8 ah[2], al[2];
#pragma unroll
        for (int ks = 0; ks < 2; ++ks) {
            ah[ks] = *(const half8*)&Qh[w * 16 + lm][ks * 32 + lg * 8];
            al[ks] = *(const half8*)&Ql[w * 16 + lm][ks * 32 + lg * 8];
        }

        float sv[4][4];  // [nt][r]
#pragma unroll
        for (int nt = 0; nt < 4; ++nt) {
            f32x4 sacc = f32x4{0.f, 0.f, 0.f, 0.f};
#pragma unroll
            for (int ks = 0; ks < 2; ++ks) {
                half8 bhv = *(const half8*)&Kh[nt * 16 + lm][ks * 32 + lg * 8];
                half8 blv = *(const half8*)&Kl[nt * 16 + lm][ks * 32 + lg * 8];
                sacc = mfma16(ah[ks], bhv, sacc);
                sacc = mfma16(ah[ks], blv, sacc);
                sacc = mfma16(al[ks], bhv, sacc);
            }
            // mask + scale + raw write
#pragma unroll
            for (int r = 0; r < 4; ++r) {
                const int q  = q0 + w * 16 + lg * 4 + r;
                const int kp = k0 + nt * 16 + lm;
                const int mk = mask[((size_t)b * SS + q) * SS + kp];
                const float s = mk ? sacc[r] * 0.125f : -1e10f;
                attn[((size_t)bh * SS + q) * SS + kp] = s;
                sv[nt][r] = s;
            }
        }
        // online stats per q-row (16-lane groups share the same q's)
#pragma unroll
        for (int r = 0; r < 4; ++r) {
            float tm = fmaxf(fmaxf(sv[0][r], sv[1][r]), fmaxf(sv[2][r], sv[3][r]));
#pragma unroll
            for (int d = 1; d < 16; d <<= 1) tm = fmaxf(tm, __shfl_xor(tm, d, 64));
            const float mn = fmaxf(mreg[r], tm);
            float ps = __expf(sv[0][r] - mn) + __expf(sv[1][r] - mn) +
                       __expf(sv[2][r] - mn) + __expf(sv[3][r] - mn);
#pragma unroll
            for (int d = 1; d < 16; d <<= 1) ps += __shfl_xor(ps, d, 64);
            lsum[r] = lsum[r] * __expf(mreg[r] - mn) + ps;
            mreg[r] = mn;
        }
    }

    if (lm == 0) {
#pragma unroll
        for (int r = 0; r < 4; ++r) {
            const int q = q0 + w * 16 + lg * 4 + r;
            mstat[(size_t)bh * SS + q] = mreg[r];
            lstat[(size_t)bh * SS + q] = lsum[r];
        }
    }
}

// ---------------------------------------------------------------------------
// PV: read raw scores, p = exp(s-m)/l, overwrite attn with p, x = P @ V.
// P-fragments loaded straight from attn in A-layout (contiguous 32B/lane).
// V from transposed global vt [B,H,D,S] -> LDS [d][k], B-frags contiguous.
// ---------------------------------------------------------------------------
__global__ __launch_bounds__(256) void pv_mfma(
    const float* __restrict__ vt, float* __restrict__ attn,
    const float* __restrict__ mstat, const float* __restrict__ lstat,
    float* __restrict__ xbuf) {
    alignas(16) __shared__ _Float16 Vh[64][PADD], Vl[64][PADD];  // [d][kpos]

    const int tid = threadIdx.x;
    const int w  = tid >> 6;
    const int l  = tid & 63;
    const int lm = l & 15;
    const int lg = l >> 4;
    const int bh = blockIdx.y;
    const int b  = bh >> 3;
    const int h  = bh & 7;
    const int q0 = blockIdx.x * 64;

    const int q_a = q0 + w * 16 + lm;  // A-fragment row q for this lane
    const float mreg = mstat[(size_t)bh * SS + q_a];
    const float rl   = 1.0f / lstat[(size_t)bh * SS + q_a];
    const size_t arow = ((size_t)bh * SS + q_a) * SS;

    f32x4 acc[4];
#pragma unroll
    for (int nt = 0; nt < 4; ++nt) acc[nt] = f32x4{0.f, 0.f, 0.f, 0.f};

    for (int k0 = 0; k0 < SS; k0 += 64) {
        __syncthreads();
        {   // stage V^T tile: rows d 0..63, cols k0..k0+63
            const float* vsrc = vt + (size_t)bh * DD * SS + k0;
#pragma unroll
            for (int p = 0; p < 4; ++p) {
                const int idx = tid + p * 256;
                const int r = idx >> 4, c4 = idx & 15;
                float4 v = *(const float4*)&vsrc[(size_t)r * SS + c4 * 4];
                split_store(v, &Vh[r][c4 * 4], &Vl[r][c4 * 4]);
            }
        }
        __syncthreads();

        half8 phi[2], plo[2];
#pragma unroll
        for (int ks = 0; ks < 2; ++ks) {
            const size_t base = arow + k0 + ks * 32 + lg * 8;
            float4 s0 = *(const float4*)&attn[base];
            float4 s1 = *(const float4*)&attn[base + 4];
            float4 p0, p1;
            p0.x = __expf(s0.x - mreg) * rl;
            p0.y = __expf(s0.y - mreg) * rl;
            p0.z = __expf(s0.z - mreg) * rl;
            p0.w = __expf(s0.w - mreg) * rl;
            p1.x = __expf(s1.x - mreg) * rl;
            p1.y = __expf(s1.y - mreg) * rl;
            p1.z = __expf(s1.z - mreg) * rl;
            p1.w = __expf(s1.w - mreg) * rl;
            *(float4*)&attn[base]     = p0;
            *(float4*)&attn[base + 4] = p1;
            half8 ph, pl;
            ph[0] = (_Float16)p0.x; pl[0] = (_Float16)(p0.x - (float)ph[0]);
            ph[1] = (_Float16)p0.y; pl[1] = (_Float16)(p0.y - (float)ph[1]);
            ph[2] = (_Float16)p0.z; pl[2] = (_Float16)(p0.z - (float)ph[2]);
            ph[3] = (_Float16)p0.w; pl[3] = (_Float16)(p0.w - (float)ph[3]);
            ph[4] = (_Float16)p1.x; pl[4] = (_Float16)(p1.x - (float)ph[4]);
            ph[5] = (_Float16)p1.y; pl[5] = (_Float16)(p1.y - (float)ph[5]);
            ph[6] = (_Float16)p1.z; pl[6] = (_Float16)(p1.z - (float)ph[6]);
            ph[7] = (_Float16)p1.w; pl[7] = (_Float16)(p1.w - (float)ph[7]);
            phi[ks] = ph; plo[ks] = pl;
        }

#pragma unroll
        for (int nt = 0; nt < 4; ++nt) {
#pragma unroll
            for (int ks = 0; ks < 2; ++ks) {
                half8 vh8 = *(const half8*)&Vh[nt * 16 + lm][ks * 32 + lg * 8];
                half8 vl8 = *(const half8*)&Vl[nt * 16 + lm][ks * 32 + lg * 8];
                acc[nt] = mfma16(phi[ks], vh8, acc[nt]);
                acc[nt] = mfma16(phi[ks], vl8, acc[nt]);
                acc[nt] = mfma16(plo[ks], vh8, acc[nt]);
            }
        }
    }

#pragma unroll
    for (int nt = 0; nt < 4; ++nt) {
#pragma unroll
        for (int r = 0; r < 4; ++r) {
            const int q = q0 + w * 16 + lg * 4 + r;
            xbuf[((size_t)b * SS + q) * HIDD + h * DD + nt * 16 + lm] = acc[nt][r];
        }
    }
}

// ---------------------------------------------------------------------------
extern "C" void kernel_launch(void* const* d_in, const int* in_sizes, int n_in,
                              void* d_out, int out_size, void* d_ws,
                              size_t ws_size, hipStream_t stream) {
    const float* q  = (const float*)d_in[0];
    const float* k  = (const float*)d_in[1];
    const float* v  = (const float*)d_in[2];
    const int* mask = (const int*)d_in[3];
    const float* Wq = (const float*)d_in[4];
    const float* bq = (const float*)d_in[5];
    const float* Wk = (const float*)d_in[6];
    const float* bk = (const float*)d_in[7];
    const float* Wv = (const float*)d_in[8];
    const float* bv = (const float*)d_in[9];
    const float* Wo = (const float*)d_in[10];
    const float* bo = (const float*)d_in[11];

    float* out  = (float*)d_out;                    // [B, S, HID]
    float* attn = out + (size_t)BB * SS * HIDD;     // [B, H, S, S]

    float* ws    = (float*)d_ws;
    float* qh    = ws;                               // [B,H,S,D]  8 MB
    float* kh    = qh + (size_t)BB * HH * SS * DD;   // [B,H,S,D]  8 MB
    float* vt    = kh + (size_t)BB * HH * SS * DD;   // [B,H,D,S]  8 MB (transposed V)
    float* xbuf  = vt + (size_t)BB * HH * DD * SS;   // [B,S,HID]  8 MB
    float* mstat = xbuf + (size_t)BB * SS * HIDD;    // [B,H,S]
    float* lstat = mstat + (size_t)BB * HH * SS;     // [B,H,S]

    dim3 gproj(NT / 64, HIDD / 64);
    proj_mfma<0><<<gproj, 256, 0, stream>>>(q, Wq, bq, qh);
    proj_mfma<0><<<gproj, 256, 0, stream>>>(k, Wk, bk, kh);
    proj_mfma<2><<<gproj, 256, 0, stream>>>(v, Wv, bv, vt);

    dim3 gattn(SS / 64, BB * HH);
    scores_mfma<<<gattn, 256, 0, stream>>>(qh, kh, mask, attn, mstat, lstat);
    pv_mfma<<<gattn, 256, 0, stream>>>(vt, attn, mstat, lstat, xbuf);

    proj_mfma<1><<<gproj, 256, 0, stream>>>(xbuf, Wo, bo, out);
}